// Round 1
// baseline (127.651 us; speedup 1.0000x reference)
//
#include <hip/hip_runtime.h>
#include <hip/hip_bf16.h>

// ContrastiveLoss (NT-Xent): B=2048, D=256, T=0.5
// loss = mean_i [ -2*dot(zh_i, zh_pos(i)) + log( sum_j exp(2*dot(zh_i, zh_j)) - e^2 ) ]

typedef __attribute__((ext_vector_type(8))) short short8;
typedef __attribute__((ext_vector_type(4))) float float4v;

#define NROWS 4096
#define DIM 256
#define NB 2048
#define TEMP_INV 2.0f
#define JCHUNKS 32
#define IBLOCKS 32
#define LDS_STRIDE 264  // shorts per LDS row: 256 + 8 pad -> 528B stride, 2-way bank alias (free)

static __device__ __forceinline__ unsigned short f2bf_rne(float f) {
    unsigned int x = __float_as_uint(f);
    unsigned int r = x + 0x7FFFu + ((x >> 16) & 1u);
    return (unsigned short)(r >> 16);
}

// K1: L2-normalize rows of [z_i; z_j] -> zf (fp32) and zb (bf16). Also zero d_out.
__global__ __launch_bounds__(256) void k_norm(const float* __restrict__ zi,
                                              const float* __restrict__ zj,
                                              float* __restrict__ zf,
                                              unsigned short* __restrict__ zb,
                                              float* __restrict__ out) {
    if (blockIdx.x == 0 && threadIdx.x == 0) *out = 0.0f;
    int wave = threadIdx.x >> 6, lane = threadIdx.x & 63;
    int row = blockIdx.x * 4 + wave;
    const float* src = (row < NB) ? (zi + (size_t)row * DIM)
                                  : (zj + (size_t)(row - NB) * DIM);
    float4 v = *(const float4*)(src + lane * 4);
    float ss = v.x * v.x + v.y * v.y + v.z * v.z + v.w * v.w;
    #pragma unroll
    for (int off = 32; off > 0; off >>= 1) ss += __shfl_xor(ss, off);
    float scale = 1.0f / fmaxf(sqrtf(ss), 1e-12f);
    float4 o;
    o.x = v.x * scale; o.y = v.y * scale; o.z = v.z * scale; o.w = v.w * scale;
    *(float4*)(zf + (size_t)row * DIM + lane * 4) = o;
    ushort4 pk;
    pk.x = f2bf_rne(o.x); pk.y = f2bf_rne(o.y);
    pk.z = f2bf_rne(o.z); pk.w = f2bf_rne(o.w);
    *(ushort4*)(zb + (size_t)row * DIM + lane * 4) = pk;
}

// K2: per-row sums of exp(2 * zh zh^T) over a 128-column chunk, via MFMA bf16.
// grid (IBLOCKS=32 i-blocks of 128 rows, JCHUNKS=32 chunks of 128 cols), block 256.
// Each wave owns 32 i-rows (two 16x16 A-tiles, A resident in regs).
__global__ __launch_bounds__(256) void k_sim(const unsigned short* __restrict__ zb,
                                             float* __restrict__ Sp) {
    __shared__ __attribute__((aligned(16))) short Bs[64 * LDS_STRIDE];
    int iblk = blockIdx.x, jchunk = blockIdx.y;
    int tid = threadIdx.x, wave = tid >> 6, lane = tid & 63;
    int m = lane & 15, q = lane >> 4;
    const short* zs = (const short*)zb;
    int ibase = iblk * 128 + wave * 32;

    // A fragments: A[m][k], m = lane&15, k = q*8 + t  (verified 16x16x32 layout)
    short8 A[2][8];
    #pragma unroll
    for (int t = 0; t < 2; t++) {
        const short* arow = zs + (size_t)(ibase + t * 16 + m) * DIM + q * 8;
        #pragma unroll
        for (int kk = 0; kk < 8; kk++) A[t][kk] = *(const short8*)(arow + kk * 32);
    }

    float accs[2][4] = {{0.f, 0.f, 0.f, 0.f}, {0.f, 0.f, 0.f, 0.f}};

    #pragma unroll
    for (int strip = 0; strip < 2; strip++) {
        int j0 = jchunk * 128 + strip * 64;
        __syncthreads();
        // stage 64 rows x 256 bf16 into LDS (row stride LDS_STRIDE)
        #pragma unroll
        for (int c = 0; c < 8; c++) {
            int chunk = c * 256 + tid;         // 0..2047, 16B chunks
            int r = chunk >> 5, cc = chunk & 31;
            *(short8*)(&Bs[r * LDS_STRIDE + cc * 8]) =
                *(const short8*)(zs + (size_t)(j0 + r) * DIM + cc * 8);
        }
        __syncthreads();

        #pragma unroll
        for (int jt = 0; jt < 4; jt++) {
            const short* brow = &Bs[(jt * 16 + m) * LDS_STRIDE + q * 8];
            float4v c0 = {0.f, 0.f, 0.f, 0.f};
            float4v c1 = {0.f, 0.f, 0.f, 0.f};
            #pragma unroll
            for (int kk = 0; kk < 8; kk++) {
                short8 b = *(const short8*)(brow + kk * 32);
                c0 = __builtin_amdgcn_mfma_f32_16x16x32_bf16(A[0][kk], b, c0, 0, 0, 0);
                c1 = __builtin_amdgcn_mfma_f32_16x16x32_bf16(A[1][kk], b, c1, 0, 0, 0);
            }
            #pragma unroll
            for (int r = 0; r < 4; r++) {
                accs[0][r] += __expf(TEMP_INV * c0[r]);
                accs[1][r] += __expf(TEMP_INV * c1[r]);
            }
        }
    }

    // reduce partial sums across the 16 lanes that share q (they hold disjoint cols)
    #pragma unroll
    for (int t = 0; t < 2; t++) {
        #pragma unroll
        for (int r = 0; r < 4; r++) {
            float s = accs[t][r];
            s += __shfl_xor(s, 1);
            s += __shfl_xor(s, 2);
            s += __shfl_xor(s, 4);
            s += __shfl_xor(s, 8);
            accs[t][r] = s;
        }
    }
    if (m == 0) {
        #pragma unroll
        for (int t = 0; t < 2; t++) {
            #pragma unroll
            for (int r = 0; r < 4; r++) {
                int irow = ibase + t * 16 + q * 4 + r;  // C/D: row = q*4 + reg
                Sp[(size_t)jchunk * NROWS + irow] = accs[t][r];
            }
        }
    }
}

// K3: per-row loss term; wave per row. pos dot in fp32, then atomic mean.
__global__ __launch_bounds__(256) void k_loss(const float* __restrict__ zf,
                                              const float* __restrict__ Sp,
                                              float* __restrict__ out) {
    int wave = threadIdx.x >> 6, lane = threadIdx.x & 63;
    int i = blockIdx.x * 4 + wave;
    int pos = (i + NB) & (NROWS - 1);
    float4 a = *(const float4*)(zf + (size_t)i * DIM + lane * 4);
    float4 b = *(const float4*)(zf + (size_t)pos * DIM + lane * 4);
    float d = a.x * b.x + a.y * b.y + a.z * b.z + a.w * b.w;
    #pragma unroll
    for (int off = 32; off > 0; off >>= 1) d += __shfl_xor(d, off);
    if (lane == 0) {
        float S = 0.0f;
        #pragma unroll
        for (int c = 0; c < JCHUNKS; c++) S += Sp[(size_t)c * NROWS + i];
        const float E2 = 7.38905609893065f;  // e^2 = exp(sim_ii)
        float term = logf(S - E2) - TEMP_INV * d;
        atomicAdd(out, term * (1.0f / NROWS));
    }
}

extern "C" void kernel_launch(void* const* d_in, const int* in_sizes, int n_in,
                              void* d_out, int out_size, void* d_ws, size_t ws_size,
                              hipStream_t stream) {
    const float* zi = (const float*)d_in[0];
    const float* zj = (const float*)d_in[1];
    float* out = (float*)d_out;
    char* ws = (char*)d_ws;
    float* zf = (float*)ws;                                      // 4 MB fp32 normalized
    unsigned short* zb = (unsigned short*)(ws + 4 * 1024 * 1024); // 2 MB bf16 normalized
    float* Sp = (float*)(ws + 6 * 1024 * 1024);                   // 512 KB partial row sums

    hipLaunchKernelGGL(k_norm, dim3(1024), dim3(256), 0, stream, zi, zj, zf, zb, out);
    hipLaunchKernelGGL(k_sim, dim3(IBLOCKS, JCHUNKS), dim3(256), 0, stream, zb, Sp);
    hipLaunchKernelGGL(k_loss, dim3(1024), dim3(256), 0, stream, zf, Sp, out);
}

// Round 2
// 84.690 us; speedup vs baseline: 1.5073x; 1.5073x over previous
//
#include <hip/hip_runtime.h>
#include <hip/hip_bf16.h>

// ContrastiveLoss (NT-Xent): B=2048, D=256, T=0.5
// loss = mean_i [ -2*dot(zh_i, zh_pos(i)) + log( sum_j exp(2*dot(zh_i, zh_j)) - e^2 ) ]

typedef __attribute__((ext_vector_type(8))) short short8;
typedef __attribute__((ext_vector_type(4))) float float4v;

#define NROWS 4096
#define DIM 256
#define NB 2048
#define TEMP_INV 2.0f
#define JCHUNKS 32
#define IBLOCKS 32
// LDS row stride in shorts: 280 shorts = 560 B = 140 dwords; 140 mod 32 = 12,
// gcd(12,32)=4 -> 16-lane phase group spreads over all 8 4-bank windows at
// exactly 2 lanes/window = conflict floor (2-way is free, m136).
#define LDS_STRIDE 280

static __device__ __forceinline__ unsigned short f2bf_rne(float f) {
    unsigned int x = __float_as_uint(f);
    unsigned int r = x + 0x7FFFu + ((x >> 16) & 1u);
    return (unsigned short)(r >> 16);
}

// K1: L2-normalize rows of [z_i; z_j] -> zf (fp32) and zb (bf16). Also zero d_out.
__global__ __launch_bounds__(256) void k_norm(const float* __restrict__ zi,
                                              const float* __restrict__ zj,
                                              float* __restrict__ zf,
                                              unsigned short* __restrict__ zb,
                                              float* __restrict__ out) {
    if (blockIdx.x == 0 && threadIdx.x == 0) *out = 0.0f;
    int wave = threadIdx.x >> 6, lane = threadIdx.x & 63;
    int row = blockIdx.x * 4 + wave;
    const float* src = (row < NB) ? (zi + (size_t)row * DIM)
                                  : (zj + (size_t)(row - NB) * DIM);
    float4 v = *(const float4*)(src + lane * 4);
    float ss = v.x * v.x + v.y * v.y + v.z * v.z + v.w * v.w;
    #pragma unroll
    for (int off = 32; off > 0; off >>= 1) ss += __shfl_xor(ss, off);
    float scale = 1.0f / fmaxf(sqrtf(ss), 1e-12f);
    float4 o;
    o.x = v.x * scale; o.y = v.y * scale; o.z = v.z * scale; o.w = v.w * scale;
    *(float4*)(zf + (size_t)row * DIM + lane * 4) = o;
    ushort4 pk;
    pk.x = f2bf_rne(o.x); pk.y = f2bf_rne(o.y);
    pk.z = f2bf_rne(o.z); pk.w = f2bf_rne(o.w);
    *(ushort4*)(zb + (size_t)row * DIM + lane * 4) = pk;
}

// K2: per-row sums of exp(2 * zh zh^T) over a 128-column chunk, via MFMA bf16.
// grid (32 i-blocks of 128 rows, 32 chunks of 128 cols), block 256.
// Each wave owns 32 i-rows (two 16x16 A-tiles, A resident in regs).
// Sp layout: [row][chunk] so K3 reads each row's 32 partials coalesced.
__global__ __launch_bounds__(256) void k_sim(const unsigned short* __restrict__ zb,
                                             float* __restrict__ Sp) {
    __shared__ __attribute__((aligned(16))) short Bs[64 * LDS_STRIDE];
    int iblk = blockIdx.x, jchunk = blockIdx.y;
    int tid = threadIdx.x, wave = tid >> 6, lane = tid & 63;
    int m = lane & 15, q = lane >> 4;
    const short* zs = (const short*)zb;
    int ibase = iblk * 128 + wave * 32;

    // A fragments: A[m][k], m = lane&15, k = q*8 + t  (verified 16x16x32 layout)
    short8 A[2][8];
    #pragma unroll
    for (int t = 0; t < 2; t++) {
        const short* arow = zs + (size_t)(ibase + t * 16 + m) * DIM + q * 8;
        #pragma unroll
        for (int kk = 0; kk < 8; kk++) A[t][kk] = *(const short8*)(arow + kk * 32);
    }

    float accs[2][4] = {{0.f, 0.f, 0.f, 0.f}, {0.f, 0.f, 0.f, 0.f}};

    #pragma unroll
    for (int strip = 0; strip < 2; strip++) {
        int j0 = jchunk * 128 + strip * 64;
        __syncthreads();
        // stage 64 rows x 256 bf16 into LDS (row stride LDS_STRIDE)
        #pragma unroll
        for (int c = 0; c < 8; c++) {
            int chunk = c * 256 + tid;         // 0..2047, 16B chunks
            int r = chunk >> 5, cc = chunk & 31;
            *(short8*)(&Bs[r * LDS_STRIDE + cc * 8]) =
                *(const short8*)(zs + (size_t)(j0 + r) * DIM + cc * 8);
        }
        __syncthreads();

        #pragma unroll
        for (int jt = 0; jt < 4; jt++) {
            const short* brow = &Bs[(jt * 16 + m) * LDS_STRIDE + q * 8];
            float4v c0 = {0.f, 0.f, 0.f, 0.f};
            float4v c1 = {0.f, 0.f, 0.f, 0.f};
            #pragma unroll
            for (int kk = 0; kk < 8; kk++) {
                short8 b = *(const short8*)(brow + kk * 32);
                c0 = __builtin_amdgcn_mfma_f32_16x16x32_bf16(A[0][kk], b, c0, 0, 0, 0);
                c1 = __builtin_amdgcn_mfma_f32_16x16x32_bf16(A[1][kk], b, c1, 0, 0, 0);
            }
            #pragma unroll
            for (int r = 0; r < 4; r++) {
                accs[0][r] += __expf(TEMP_INV * c0[r]);
                accs[1][r] += __expf(TEMP_INV * c1[r]);
            }
        }
    }

    // reduce partial sums across the 16 lanes that share q (disjoint cols)
    #pragma unroll
    for (int t = 0; t < 2; t++) {
        #pragma unroll
        for (int r = 0; r < 4; r++) {
            float s = accs[t][r];
            s += __shfl_xor(s, 1);
            s += __shfl_xor(s, 2);
            s += __shfl_xor(s, 4);
            s += __shfl_xor(s, 8);
            accs[t][r] = s;
        }
    }
    if (m == 0) {
        #pragma unroll
        for (int t = 0; t < 2; t++) {
            #pragma unroll
            for (int r = 0; r < 4; r++) {
                int irow = ibase + t * 16 + q * 4 + r;  // C/D: row = q*4 + reg
                Sp[(size_t)irow * JCHUNKS + jchunk] = accs[t][r];
            }
        }
    }
}

// K3: per-row loss terms. 128 blocks x 4 waves; each wave handles 8 rows.
// Block-level LDS reduction -> ONE atomicAdd per block (128 total).
__global__ __launch_bounds__(256) void k_loss(const float* __restrict__ zf,
                                              const float* __restrict__ Sp,
                                              float* __restrict__ out) {
    __shared__ float red[4];
    int wave = threadIdx.x >> 6, lane = threadIdx.x & 63;
    float wsum = 0.0f;
    #pragma unroll
    for (int t = 0; t < 8; t++) {
        int i = blockIdx.x * 32 + wave * 8 + t;
        int pos = (i + NB) & (NROWS - 1);
        float4 a = *(const float4*)(zf + (size_t)i * DIM + lane * 4);
        float4 b = *(const float4*)(zf + (size_t)pos * DIM + lane * 4);
        float d = a.x * b.x + a.y * b.y + a.z * b.z + a.w * b.w;
        float s = (lane < JCHUNKS) ? Sp[(size_t)i * JCHUNKS + lane] : 0.0f;
        #pragma unroll
        for (int off = 32; off > 0; off >>= 1) d += __shfl_xor(d, off);
        #pragma unroll
        for (int off = 16; off > 0; off >>= 1) s += __shfl_xor(s, off);
        if (lane == 0) {
            const float E2 = 7.38905609893065f;  // exp(sim_ii) = e^2
            wsum += logf(s - E2) - TEMP_INV * d;
        }
    }
    if (lane == 0) red[wave] = wsum;
    __syncthreads();
    if (threadIdx.x == 0) {
        float t = (red[0] + red[1] + red[2] + red[3]) * (1.0f / NROWS);
        atomicAdd(out, t);
    }
}

extern "C" void kernel_launch(void* const* d_in, const int* in_sizes, int n_in,
                              void* d_out, int out_size, void* d_ws, size_t ws_size,
                              hipStream_t stream) {
    const float* zi = (const float*)d_in[0];
    const float* zj = (const float*)d_in[1];
    float* out = (float*)d_out;
    char* ws = (char*)d_ws;
    float* zf = (float*)ws;                                       // 4 MB fp32 normalized
    unsigned short* zb = (unsigned short*)(ws + 4 * 1024 * 1024); // 2 MB bf16 normalized
    float* Sp = (float*)(ws + 6 * 1024 * 1024);                   // 512 KB partials [row][chunk]

    hipLaunchKernelGGL(k_norm, dim3(1024), dim3(256), 0, stream, zi, zj, zf, zb, out);
    hipLaunchKernelGGL(k_sim, dim3(IBLOCKS, JCHUNKS), dim3(256), 0, stream, zb, Sp);
    hipLaunchKernelGGL(k_loss, dim3(128), dim3(256), 0, stream, zf, Sp, out);
}